// Round 2
// baseline (114.034 us; speedup 1.0000x reference)
//
#include <hip/hip_runtime.h>
#include <math.h>

#define NRES   4096
#define TROWS  4
#define GRID   (NRES / TROWS)      // 1024 blocks -> exactly 4 blocks/CU, uniform work
#define HB_BLOCKS (NRES / 256)     // 16
#define PSTRIDE (GRID * 256)       // 262144

typedef int i32x2 __attribute__((ext_vector_type(2)));

__device__ __forceinline__ float wave_sum(float v) {
#pragma unroll
    for (int off = 32; off > 0; off >>= 1) v += __shfl_down(v, off, 64);
    return v;
}

// raw v_sqrt_f32 (≈1 ulp), skips libm's IEEE fixup sequence
__device__ __forceinline__ float fsqrt(float x) { return __builtin_amdgcn_sqrtf(x); }

// load point i from interleaved ca
__device__ __forceinline__ void ldp(const float* __restrict__ ca, int i,
                                    float& x, float& y, float& z) {
    x = ca[3 * i]; y = ca[3 * i + 1]; z = ca[3 * i + 2];
}

// 4 contact terms: one K float4 vs 4 columns (in registers)
__device__ __forceinline__ float c4(float4 kv, float4 cx, float4 cy, float4 cz,
                                    float xi, float yi, float zi, float s) {
    float dx, dy, dz, D, t;
    dx = xi - cx.x; dy = yi - cy.x; dz = zi - cz.x;
    D  = fsqrt(fmaf(dx, dx, fmaf(dy, dy, dz * dz)));
    t  = fmaf(8.f, kv.x, D - 8.f);   // D - 8(1-k)
    s  = fmaf(t, t, s);

    dx = xi - cx.y; dy = yi - cy.y; dz = zi - cz.y;
    D  = fsqrt(fmaf(dx, dx, fmaf(dy, dy, dz * dz)));
    t  = fmaf(8.f, kv.y, D - 8.f);
    s  = fmaf(t, t, s);

    dx = xi - cx.z; dy = yi - cy.z; dz = zi - cz.z;
    D  = fsqrt(fmaf(dx, dx, fmaf(dy, dy, dz * dz)));
    t  = fmaf(8.f, kv.z, D - 8.f);
    s  = fmaf(t, t, s);

    dx = xi - cx.w; dy = yi - cy.w; dz = zi - cz.w;
    D  = fsqrt(fmaf(dx, dx, fmaf(dy, dy, dz * dz)));
    t  = fmaf(8.f, kv.w, D - 8.f);
    s  = fmaf(t, t, s);
    return s;
}

// ZERO-LDS variant. ca (48 KB) is L1/L2-resident by construction (every block
// reads it), so columns come straight from global as 3 aligned float4s per
// 4-column group, reshuffled in registers for free. Rows are wave-uniform
// scalar loads. Clash gathers hit the same cached 48 KB. This removes the
// serial 48 KB LDS fill + barrier in front of the K stream and doubles
// latency-hiding to 16 waves/CU (4 blocks/CU uniform). K streamed once
// (64 MiB): the HBM floor for this kernel is ~10.7 us.
__global__ __launch_bounds__(256, 4) void energy_kernel(const float* __restrict__ ca,
                                                        const float* __restrict__ K,
                                                        const int* __restrict__ pairs,
                                                        float4* __restrict__ partial,
                                                        int npairs) {
    __shared__ float red[4][4];
    const int tid = threadIdx.x;
    const int b   = blockIdx.x;

    const int rbase = b * TROWS;
    const float* Kt = K + (size_t)rbase * NRES;
    const int j0 = tid << 2;

    // chunk-0 K prefetch: first VMEM the wave issues (no barrier in front)
    float4 va[TROWS], vbuf[TROWS];
#pragma unroll
    for (int r = 0; r < TROWS; ++r)
        va[r] = *(const float4*)(Kt + (size_t)r * NRES + j0);

    // chunk-0 column prefetch: 4 interleaved float3 points = 3 aligned float4
    float4 la[3], lb[3];
#pragma unroll
    for (int q = 0; q < 3; ++q)
        la[q] = *(const float4*)(ca + 3 * j0 + 4 * q);

    // clash pair indices (each thread owns <=2 pairs now: PSTRIDE=262144)
    const int pbase = b * 256 + tid;
    const i32x2* pairs2 = (const i32x2*)pairs;
    i32x2 pr0 = pairs2[pbase];                       // < 262144, always valid
    const bool has1 = (pbase + PSTRIDE) < npairs;
    i32x2 pr1 = has1 ? pairs2[pbase + PSTRIDE] : (i32x2){0, 0};

    // row coords: wave-uniform addresses -> scalar loads
    float xi[TROWS], yi[TROWS], zi[TROWS];
#pragma unroll
    for (int r = 0; r < TROWS; ++r)
        ldp(ca, rbase + r, xi[r], yi[r], zi[r]);

    // ---------------- contact: 4 column chunks of 1024 ----------------
    float contact = 0.f, contact2 = 0.f;
#pragma unroll
    for (int c = 0; c < 4; ++c) {
        float4* cur  = (c & 1) ? vbuf : va;
        float4* nxt  = (c & 1) ? va : vbuf;
        float4* curc = (c & 1) ? lb : la;
        float4* nxtc = (c & 1) ? la : lb;
        if (c < 3) {
            const int jn = j0 + ((c + 1) << 10);
#pragma unroll
            for (int r = 0; r < TROWS; ++r)
                nxt[r] = *(const float4*)(Kt + (size_t)r * NRES + jn);
#pragma unroll
            for (int q = 0; q < 3; ++q)
                nxtc[q] = *(const float4*)(ca + 3 * jn + 4 * q);
        }
        // unpack 4 columns (x,y,z) from 3 float4 -> pure register selects
        const float4 cx = make_float4(curc[0].x, curc[0].w, curc[1].z, curc[2].y);
        const float4 cy = make_float4(curc[0].y, curc[1].x, curc[1].w, curc[2].z);
        const float4 cz = make_float4(curc[0].z, curc[1].y, curc[2].x, curc[2].w);

        contact  = c4(cur[0], cx, cy, cz, xi[0], yi[0], zi[0], contact);
        contact2 = c4(cur[1], cx, cy, cz, xi[1], yi[1], zi[1], contact2);
        contact  = c4(cur[2], cx, cy, cz, xi[2], yi[2], zi[2], contact);
        contact2 = c4(cur[3], cx, cy, cz, xi[3], yi[3], zi[3], contact2);
    }
    contact += contact2;

    // ---------------- clash: gathers from (cached) global ca ----------------
    float clash = 0.f;
    {
        float ax, ay, az, bx, by, bz, dx, dy, dz, d, r;
        ldp(ca, pr0.x, ax, ay, az);
        ldp(ca, pr0.y, bx, by, bz);
        dx = ax - bx; dy = ay - by; dz = az - bz;
        d = fsqrt(fmaxf(fmaf(dx, dx, fmaf(dy, dy, dz * dz)), 1e-12f));
        r = fmaxf(3.2f - d, 0.f); clash = fmaf(r, r, clash);

        if (has1) {
            ldp(ca, pr1.x, ax, ay, az);
            ldp(ca, pr1.y, bx, by, bz);
            dx = ax - bx; dy = ay - by; dz = az - bz;
            d = fsqrt(fmaxf(fmaf(dx, dx, fmaf(dy, dy, dz * dz)), 1e-12f));
            r = fmaxf(3.2f - d, 0.f); clash = fmaf(r, r, clash);
        }
    }

    // ---------------- bond + hb: blocks 0..15, from (cached) global ----------------
    float bond = 0.f, hb = 0.f;
    if (b < HB_BLOCKS) {
        const int i = b * 256 + tid;
        const int n = NRES;

        float cax, cay, caz, nx1, ny1, nz1;
        ldp(ca, i, cax, cay, caz);

        if (i < n - 1) {
            ldp(ca, i + 1, nx1, ny1, nz1);
            float dx = nx1 - cax, dy = ny1 - cay, dz = nz1 - caz;
            float d  = sqrtf(fmaf(dx, dx, fmaf(dy, dy, dz * dz)));
            float t  = d - 3.8f;
            bond = t * t;
        }

        if (i < n - 2) {
            float vx = nx1 - cax, vy = ny1 - cay, vz = nz1 - caz;
            float inv = 1.f / (sqrtf(vx*vx + vy*vy + vz*vz) + 1e-8f);
            float ux = vx*inv, uy = vy*inv, uz = vz*inv;

            float upx, upy, upz;
            if (i == 0) { upx = ux; upy = uy; upz = uz; }
            else {
                float mx, my, mz;
                ldp(ca, i - 1, mx, my, mz);
                float wx = cax-mx, wy = cay-my, wz = caz-mz;
                float inv2 = 1.f / (sqrtf(wx*wx + wy*wy + wz*wz) + 1e-8f);
                upx = wx*inv2; upy = wy*inv2; upz = wz*inv2;
            }

            float vcx = 0.38f*ux,  vcy = 0.38f*uy,  vcz = 0.38f*uz;
            float vnx = -0.38f*upx, vny = -0.38f*upy, vnz = -0.38f*upz;
            float px = vcy*vnz - vcz*vny;
            float py = vcz*vnx - vcx*vnz;
            float pz = vcx*vny - vcy*vnx;
            float pn = sqrtf(px*px + py*py + pz*pz);
            if (pn > 1e-6f) {
                float ipn = 1.f / fmaxf(pn, 1e-12f);
                px *= ipn; py *= ipn; pz *= ipn;
            }
            float ox = cax + vcx + 1.24f*px;
            float oy = cay + vcy + 1.24f*py;
            float oz = caz + vcz + 1.24f*pz;

            // points jj-1, jj for jj = i+2..i+5
            float pjx, pjy, pjz;          // point jj-1 (starts at i+1)
            pjx = nx1; pjy = ny1; pjz = nz1;
#pragma unroll
            for (int off = 2; off <= 5; ++off) {
                int jj = i + off;
                if (jj < n) {
                    float cjx, cjy, cjz;
                    ldp(ca, jj, cjx, cjy, cjz);
                    float qx = cjx-pjx, qy = cjy-pjy, qz = cjz-pjz;
                    float invq = 1.f / (sqrtf(qx*qx + qy*qy + qz*qz) + 1e-8f);
                    float njx = cjx - 0.38f*qx*invq;
                    float njy = cjy - 0.38f*qy*invq;
                    float njz = cjz - 0.38f*qz*invq;
                    float ddx = ox-njx, ddy = oy-njy, ddz = oz-njz;
                    float d = sqrtf(ddx*ddx + ddy*ddy + ddz*ddz);
                    if (d > 2.5f && d < 3.5f) {
                        float z = (d - 2.95f) * (1.0f / 0.3f);
                        hb -= 0.5f * expf(-z*z);
                    }
                    pjx = cjx; pjy = cjy; pjz = cjz;
                }
            }
        }
    }

    // ---------------- block reduce -> partial[b] ----------------
    float vbo = wave_sum(bond);
    float vcl = wave_sum(clash);
    float vco = wave_sum(contact);
    float vhb = wave_sum(hb);
    const int wave = tid >> 6;
    if ((tid & 63) == 0) {
        red[wave][0] = vbo; red[wave][1] = vcl; red[wave][2] = vco; red[wave][3] = vhb;
    }
    __syncthreads();
    if (tid == 0) {
        float4 o;
        o.x = red[0][0] + red[1][0] + red[2][0] + red[3][0];
        o.y = red[0][1] + red[1][1] + red[2][1] + red[3][1];
        o.z = red[0][2] + red[1][2] + red[2][2] + red[3][2];
        o.w = red[0][3] + red[1][3] + red[2][3] + red[3][3];
        partial[b] = o;
    }
}

// ---- reduce GRID partials, apply weights ----
__global__ __launch_bounds__(256) void finalize_kernel(const float4* __restrict__ partial,
                                                       float* __restrict__ out,
                                                       int n, int npairs) {
    __shared__ float red[4][4];
    const int tid = threadIdx.x;
    float vb = 0.f, vc = 0.f, vk = 0.f, vh = 0.f;
#pragma unroll
    for (int s = 0; s < GRID; s += 256) {
        float4 a = partial[tid + s];
        vb += a.x; vc += a.y; vk += a.z; vh += a.w;
    }
    vb = wave_sum(vb); vc = wave_sum(vc); vk = wave_sum(vk); vh = wave_sum(vh);
    const int wave = tid >> 6;
    if ((tid & 63) == 0) {
        red[wave][0] = vb; red[wave][1] = vc; red[wave][2] = vk; red[wave][3] = vh;
    }
    __syncthreads();
    if (tid == 0) {
        float bond    = red[0][0] + red[1][0] + red[2][0] + red[3][0];
        float clash   = red[0][1] + red[1][1] + red[2][1] + red[3][1];
        float contact = red[0][2] + red[1][2] + red[2][2] + red[3][2];
        float hb      = red[0][3] + red[1][3] + red[2][3] + red[3][3];
        float inv_nn  = 1.f / ((float)n * (float)n);
        out[0] = 30.f * bond / (float)(n - 1)
               + 50.f * clash / (float)npairs
               + 5.f  * contact * inv_nn
               + 4.f  * hb * inv_nn;
    }
}

extern "C" void kernel_launch(void* const* d_in, const int* in_sizes, int n_in,
                              void* d_out, int out_size, void* d_ws, size_t ws_size,
                              hipStream_t stream) {
    const float* ca    = (const float*)d_in[0];
    const float* K     = (const float*)d_in[1];
    const int*   pairs = (const int*)d_in[2];   // int32 on device (x64 disabled)
    float* out = (float*)d_out;
    float4* partial = (float4*)d_ws;            // GRID float4 = 16 KB

    int n      = in_sizes[0] / 3;               // 4096
    int npairs = in_sizes[2] / 2;               // 500000

    energy_kernel<<<GRID, 256, 0, stream>>>(ca, K, pairs, partial, npairs);
    finalize_kernel<<<1, 256, 0, stream>>>(partial, out, n, npairs);
}

// Round 3
// 113.089 us; speedup vs baseline: 1.0084x; 1.0084x over previous
//
#include <hip/hip_runtime.h>
#include <math.h>

#define NRES   4096
#define TROWS  8
#define GRID   (NRES / TROWS)      // 512 blocks, one 8-row tile each
#define HB_BLOCKS (NRES / 256)     // 16
#define PSTRIDE (GRID * 256)       // 131072

typedef int i32x2 __attribute__((ext_vector_type(2)));

// last-block-done ticket: zero at module load; last block resets to 0 each run,
// so graph replays and rocprof counter passes always start from 0.
__device__ int g_ticket = 0;

__device__ __forceinline__ float wave_sum(float v) {
#pragma unroll
    for (int off = 32; off > 0; off >>= 1) v += __shfl_down(v, off, 64);
    return v;
}

// raw v_sqrt_f32 (≈1 ulp), skips libm's IEEE fixup sequence
__device__ __forceinline__ float fsqrt(float x) { return __builtin_amdgcn_sqrtf(x); }

// 4 contact terms: one K float4 vs 4 LDS columns
__device__ __forceinline__ float c4(float4 kv, float4 cx, float4 cy, float4 cz,
                                    float xi, float yi, float zi, float s) {
    float dx, dy, dz, D, t;
    dx = xi - cx.x; dy = yi - cy.x; dz = zi - cz.x;
    D  = fsqrt(fmaf(dx, dx, fmaf(dy, dy, dz * dz)));
    t  = fmaf(8.f, kv.x, D - 8.f);   // D - 8(1-k)
    s  = fmaf(t, t, s);

    dx = xi - cx.y; dy = yi - cy.y; dz = zi - cz.y;
    D  = fsqrt(fmaf(dx, dx, fmaf(dy, dy, dz * dz)));
    t  = fmaf(8.f, kv.y, D - 8.f);
    s  = fmaf(t, t, s);

    dx = xi - cx.z; dy = yi - cy.z; dz = zi - cz.z;
    D  = fsqrt(fmaf(dx, dx, fmaf(dy, dy, dz * dz)));
    t  = fmaf(8.f, kv.z, D - 8.f);
    s  = fmaf(t, t, s);

    dx = xi - cx.w; dy = yi - cy.w; dz = zi - cz.w;
    D  = fsqrt(fmaf(dx, dx, fmaf(dy, dy, dz * dz)));
    t  = fmaf(8.f, kv.w, D - 8.f);
    s  = fmaf(t, t, s);
    return s;
}

// Proven R1 structure (LDS ca table: clash gathers from LDS beat global by
// ~12 us, round-2 A/B) + two additive changes:
//  1. K chunks 0 AND 1 prefetched before the 48KB LDS fill -> fill+barrier
//     fully hidden under 16KB/wave of K loads in flight; loop reloads the
//     consumed buffer with chunk c+2 (no ping-pong swap).
//  2. Fused finalize: last-block-done ticket replaces the second dispatch.
//     Reduction arithmetic is bitwise-identical to the old finalize_kernel.
__global__ __launch_bounds__(256, 2) void energy_kernel(const float* __restrict__ ca,
                                                        const float* __restrict__ K,
                                                        const int* __restrict__ pairs,
                                                        float4* __restrict__ partial,
                                                        float* __restrict__ out,
                                                        int npairs) {
    __shared__ float sx[NRES], sy[NRES], sz[NRES];   // 48 KB
    __shared__ float red[4][4];
    __shared__ int lastflag;
    const int tid = threadIdx.x;
    const int b   = blockIdx.x;

    const int rbase = b * TROWS;
    const float* Kt = K + (size_t)rbase * NRES;
    const int j0 = tid << 2;

    // K chunks 0 and 1 in flight before LDS staging (no dependence on LDS)
    float4 va[TROWS], vbuf[TROWS];
#pragma unroll
    for (int r = 0; r < TROWS; ++r)
        va[r] = *(const float4*)(Kt + (size_t)r * NRES + j0);
#pragma unroll
    for (int r = 0; r < TROWS; ++r)
        vbuf[r] = *(const float4*)(Kt + (size_t)r * NRES + j0 + 1024);

    // preload clash pair indices (resolve after contact)
    const int pbase = b * 256 + tid;
    const i32x2* pairs2 = (const i32x2*)pairs;
    i32x2 pr0 = pairs2[pbase];                 // < 131072  always valid
    i32x2 pr1 = pairs2[pbase + PSTRIDE];       // < 262144  always valid
    i32x2 pr2 = pairs2[pbase + 2 * PSTRIDE];   // < 393216  always valid (npairs=500000)
    const bool has3 = (pbase + 3 * PSTRIDE) < npairs;
    i32x2 pr3 = has3 ? pairs2[pbase + 3 * PSTRIDE] : (i32x2){0, 0};

    for (int j = tid; j < NRES; j += 256) {
        sx[j] = ca[3 * j + 0];
        sy[j] = ca[3 * j + 1];
        sz[j] = ca[3 * j + 2];
    }
    __syncthreads();

    // ---------------- contact: single 8-row tile, 2-deep K pipeline ----------------
    float xi[TROWS], yi[TROWS], zi[TROWS];
#pragma unroll
    for (int r = 0; r < TROWS; ++r) {
        xi[r] = sx[rbase + r]; yi[r] = sy[rbase + r]; zi[r] = sz[rbase + r];
    }

    float contact = 0.f, contact2 = 0.f;
#pragma unroll
    for (int c = 0; c < 4; ++c) {               // 4 column chunks of 1024
        float4* cur = (c & 1) ? vbuf : va;
        const int jc = j0 + (c << 10);
        const float4 cx = *(const float4*)&sx[jc];
        const float4 cy = *(const float4*)&sy[jc];
        const float4 cz = *(const float4*)&sz[jc];
#pragma unroll
        for (int r = 0; r < TROWS; r += 2) {
            contact  = c4(cur[r],     cx, cy, cz, xi[r],     yi[r],     zi[r],     contact);
            contact2 = c4(cur[r + 1], cx, cy, cz, xi[r + 1], yi[r + 1], zi[r + 1], contact2);
        }
        if (c < 2) {                            // reload consumed buffer with chunk c+2
            const int jn = j0 + ((c + 2) << 10);
#pragma unroll
            for (int r = 0; r < TROWS; ++r)
                cur[r] = *(const float4*)(Kt + (size_t)r * NRES + jn);
        }
    }
    contact += contact2;

    // ---------------- clash: preloaded indices, gathers from LDS ----------------
    float clash = 0.f;
    {
        float dx, dy, dz, d, r;
        dx = sx[pr0.x] - sx[pr0.y]; dy = sy[pr0.x] - sy[pr0.y]; dz = sz[pr0.x] - sz[pr0.y];
        d = fsqrt(fmaxf(fmaf(dx, dx, fmaf(dy, dy, dz * dz)), 1e-12f));
        r = fmaxf(3.2f - d, 0.f); clash = fmaf(r, r, clash);

        dx = sx[pr1.x] - sx[pr1.y]; dy = sy[pr1.x] - sy[pr1.y]; dz = sz[pr1.x] - sz[pr1.y];
        d = fsqrt(fmaxf(fmaf(dx, dx, fmaf(dy, dy, dz * dz)), 1e-12f));
        r = fmaxf(3.2f - d, 0.f); clash = fmaf(r, r, clash);

        dx = sx[pr2.x] - sx[pr2.y]; dy = sy[pr2.x] - sy[pr2.y]; dz = sz[pr2.x] - sz[pr2.y];
        d = fsqrt(fmaxf(fmaf(dx, dx, fmaf(dy, dy, dz * dz)), 1e-12f));
        r = fmaxf(3.2f - d, 0.f); clash = fmaf(r, r, clash);

        if (has3) {
            dx = sx[pr3.x] - sx[pr3.y]; dy = sy[pr3.x] - sy[pr3.y]; dz = sz[pr3.x] - sz[pr3.y];
            d = fsqrt(fmaxf(fmaf(dx, dx, fmaf(dy, dy, dz * dz)), 1e-12f));
            r = fmaxf(3.2f - d, 0.f); clash = fmaf(r, r, clash);
        }
    }

    // ---------------- bond + hb: blocks 0..15, from LDS ----------------
    float bond = 0.f, hb = 0.f;
    if (b < HB_BLOCKS) {
        const int i = b * 256 + tid;
        const int n = NRES;

        if (i < n - 1) {
            float dx = sx[i+1]-sx[i], dy = sy[i+1]-sy[i], dz = sz[i+1]-sz[i];
            float d  = sqrtf(fmaf(dx, dx, fmaf(dy, dy, dz * dz)));
            float t  = d - 3.8f;
            bond = t * t;
        }

        if (i < n - 2) {
            float cax = sx[i], cay = sy[i], caz = sz[i];
            float vx = sx[i+1]-cax, vy = sy[i+1]-cay, vz = sz[i+1]-caz;
            float inv = 1.f / (sqrtf(vx*vx + vy*vy + vz*vz) + 1e-8f);
            float ux = vx*inv, uy = vy*inv, uz = vz*inv;

            float upx, upy, upz;
            if (i == 0) { upx = ux; upy = uy; upz = uz; }
            else {
                float wx = cax-sx[i-1], wy = cay-sy[i-1], wz = caz-sz[i-1];
                float inv2 = 1.f / (sqrtf(wx*wx + wy*wy + wz*wz) + 1e-8f);
                upx = wx*inv2; upy = wy*inv2; upz = wz*inv2;
            }

            float vcx = 0.38f*ux,  vcy = 0.38f*uy,  vcz = 0.38f*uz;
            float vnx = -0.38f*upx, vny = -0.38f*upy, vnz = -0.38f*upz;
            float px = vcy*vnz - vcz*vny;
            float py = vcz*vnx - vcx*vnz;
            float pz = vcx*vny - vcy*vnx;
            float pn = sqrtf(px*px + py*py + pz*pz);
            if (pn > 1e-6f) {
                float ipn = 1.f / fmaxf(pn, 1e-12f);
                px *= ipn; py *= ipn; pz *= ipn;
            }
            float ox = cax + vcx + 1.24f*px;
            float oy = cay + vcy + 1.24f*py;
            float oz = caz + vcz + 1.24f*pz;

#pragma unroll
            for (int off = 2; off <= 5; ++off) {
                int jj = i + off;
                if (jj < n) {
                    float cjx = sx[jj], cjy = sy[jj], cjz = sz[jj];
                    float qx = cjx-sx[jj-1], qy = cjy-sy[jj-1], qz = cjz-sz[jj-1];
                    float invq = 1.f / (sqrtf(qx*qx + qy*qy + qz*qz) + 1e-8f);
                    float njx = cjx - 0.38f*qx*invq;
                    float njy = cjy - 0.38f*qy*invq;
                    float njz = cjz - 0.38f*qz*invq;
                    float ddx = ox-njx, ddy = oy-njy, ddz = oz-njz;
                    float d = sqrtf(ddx*ddx + ddy*ddy + ddz*ddz);
                    if (d > 2.5f && d < 3.5f) {
                        float z = (d - 2.95f) * (1.0f / 0.3f);
                        hb -= 0.5f * expf(-z*z);
                    }
                }
            }
        }
    }

    // ---------------- block reduce -> partial[b] ----------------
    float vbo = wave_sum(bond);
    float vcl = wave_sum(clash);
    float vco = wave_sum(contact);
    float vhb = wave_sum(hb);
    const int wave = tid >> 6;
    if ((tid & 63) == 0) {
        red[wave][0] = vbo; red[wave][1] = vcl; red[wave][2] = vco; red[wave][3] = vhb;
    }
    __syncthreads();
    if (tid == 0) {
        float4 o;
        o.x = red[0][0] + red[1][0] + red[2][0] + red[3][0];
        o.y = red[0][1] + red[1][1] + red[2][1] + red[3][1];
        o.z = red[0][2] + red[1][2] + red[2][2] + red[3][2];
        o.w = red[0][3] + red[1][3] + red[2][3] + red[3][3];
        partial[b] = o;
        __threadfence();                           // partial visible device-wide
        int old = atomicAdd(&g_ticket, 1);         // device-scope RMW
        lastflag = (old == GRID - 1);
    }
    __syncthreads();

    // ---------------- fused finalize: last block only ----------------
    if (lastflag) {
        __threadfence();                           // acquire partials from all XCDs
        const volatile float* pv = (const volatile float*)partial;
        float fb = 0.f, fc = 0.f, fk = 0.f, fh = 0.f;
#pragma unroll
        for (int s = 0; s < GRID; s += 256) {
            const int idx = (tid + s) << 2;
            fb += pv[idx + 0]; fc += pv[idx + 1]; fk += pv[idx + 2]; fh += pv[idx + 3];
        }
        fb = wave_sum(fb); fc = wave_sum(fc); fk = wave_sum(fk); fh = wave_sum(fh);
        __syncthreads();                           // red[] reuse: prior use complete
        if ((tid & 63) == 0) {
            red[wave][0] = fb; red[wave][1] = fc; red[wave][2] = fk; red[wave][3] = fh;
        }
        __syncthreads();
        if (tid == 0) {
            float bondS    = red[0][0] + red[1][0] + red[2][0] + red[3][0];
            float clashS   = red[0][1] + red[1][1] + red[2][1] + red[3][1];
            float contactS = red[0][2] + red[1][2] + red[2][2] + red[3][2];
            float hbS      = red[0][3] + red[1][3] + red[2][3] + red[3][3];
            const float n  = (float)NRES;
            float inv_nn   = 1.f / (n * n);
            out[0] = 30.f * bondS / (n - 1.f)
                   + 50.f * clashS / (float)npairs
                   + 5.f  * contactS * inv_nn
                   + 4.f  * hbS * inv_nn;
            g_ticket = 0;                          // reset for next graph replay
        }
    }
}

extern "C" void kernel_launch(void* const* d_in, const int* in_sizes, int n_in,
                              void* d_out, int out_size, void* d_ws, size_t ws_size,
                              hipStream_t stream) {
    const float* ca    = (const float*)d_in[0];
    const float* K     = (const float*)d_in[1];
    const int*   pairs = (const int*)d_in[2];   // int32 on device (x64 disabled)
    float* out = (float*)d_out;
    float4* partial = (float4*)d_ws;            // GRID float4 = 8 KB

    int npairs = in_sizes[2] / 2;               // 500000

    energy_kernel<<<GRID, 256, 0, stream>>>(ca, K, pairs, partial, out, npairs);
}

// Round 5
// 107.233 us; speedup vs baseline: 1.0634x; 1.0546x over previous
//
#include <hip/hip_runtime.h>
#include <math.h>

#define NRES   4096
#define TROWS  8
#define GRID   (NRES / TROWS)      // 512 blocks, one contiguous 128KB K-slab each
#define HB_BLOCKS (NRES / 256)     // 16
#define PSTRIDE (GRID * 256)       // 131072

typedef int i32x2 __attribute__((ext_vector_type(2)));
typedef float f32x4 __attribute__((ext_vector_type(4)));   // native vector for nontemporal builtin

__device__ __forceinline__ float wave_sum(float v) {
#pragma unroll
    for (int off = 32; off > 0; off >>= 1) v += __shfl_down(v, off, 64);
    return v;
}

// raw v_sqrt_f32 (≈1 ulp), skips libm's IEEE fixup sequence
__device__ __forceinline__ float fsqrt(float x) { return __builtin_amdgcn_sqrtf(x); }

// non-temporal float4 load: read-once K stream, evict-first, no L1 pollution,
// and does NOT evict dirty poison/restore lines from L2/L3 (no writeback storm).
// __builtin_nontemporal_load requires a native vector type (not HIP float4).
__device__ __forceinline__ float4 ldnt(const float* p) {
    f32x4 v = __builtin_nontemporal_load((const f32x4*)p);
    return make_float4(v.x, v.y, v.z, v.w);
}

// 4 contact terms: one K float4 vs 4 columns (in registers)
__device__ __forceinline__ float c4(float4 kv, float4 cx, float4 cy, float4 cz,
                                    float xi, float yi, float zi, float s) {
    float dx, dy, dz, D, t;
    dx = xi - cx.x; dy = yi - cy.x; dz = zi - cz.x;
    D  = fsqrt(fmaf(dx, dx, fmaf(dy, dy, dz * dz)));
    t  = fmaf(8.f, kv.x, D - 8.f);   // D - 8(1-k)
    s  = fmaf(t, t, s);

    dx = xi - cx.y; dy = yi - cy.y; dz = zi - cz.y;
    D  = fsqrt(fmaf(dx, dx, fmaf(dy, dy, dz * dz)));
    t  = fmaf(8.f, kv.y, D - 8.f);
    s  = fmaf(t, t, s);

    dx = xi - cx.z; dy = yi - cy.z; dz = zi - cz.z;
    D  = fsqrt(fmaf(dx, dx, fmaf(dy, dy, dz * dz)));
    t  = fmaf(8.f, kv.z, D - 8.f);
    s  = fmaf(t, t, s);

    dx = xi - cx.w; dy = yi - cy.w; dz = zi - cz.w;
    D  = fsqrt(fmaf(dx, dx, fmaf(dy, dy, dz * dz)));
    t  = fmaf(8.f, kv.w, D - 8.f);
    s  = fmaf(t, t, s);
    return s;
}

// R1 structure (proven 101.8: LDS ca table, 2-dispatch reduce — fused
// ticket+threadfence finalize REGRESSED 11us in R3, device-scope fences are
// expensive on non-coherent XCD L2s). ONE change vs R1: the contact loop walks
// the block's 128KB K-slab in MEMORY ORDER (row-outer, chunk-inner) with an
// 8-deep register ring -> one sequential HBM pointer per block (512 streams
// device-wide) instead of 8 interleaved 16KB-strided pointers (4096 streams,
// DRAM row thrash suspect for the kernel running ~3x its 10.7us K floor).
// Column vectors for all 4 chunks are hoisted to registers so the reorder adds
// no LDS traffic. K loads are non-temporal (read-once).
__global__ __launch_bounds__(256, 2) void energy_kernel(const float* __restrict__ ca,
                                                        const float* __restrict__ K,
                                                        const int* __restrict__ pairs,
                                                        float4* __restrict__ partial,
                                                        int npairs) {
    __shared__ float sx[NRES], sy[NRES], sz[NRES];   // 48 KB
    __shared__ float red[4][4];
    const int tid = threadIdx.x;
    const int b   = blockIdx.x;

    const int rbase = b * TROWS;
    const float* Kt = K + (size_t)rbase * NRES;
    const int j0 = tid << 2;

    // ring prefetch: steps 0..7 (rows 0-1, all 4 chunks) in memory order,
    // issued before the LDS fill (drained by its barrier -> free latency)
    float4 ring[8];
#pragma unroll
    for (int s = 0; s < 8; ++s)
        ring[s] = ldnt(Kt + (size_t)(s >> 2) * NRES + ((s & 3) << 10) + j0);

    // preload clash pair indices (resolve after contact)
    const int pbase = b * 256 + tid;
    const i32x2* pairs2 = (const i32x2*)pairs;
    i32x2 pr0 = pairs2[pbase];                 // < 131072  always valid
    i32x2 pr1 = pairs2[pbase + PSTRIDE];       // < 262144  always valid
    i32x2 pr2 = pairs2[pbase + 2 * PSTRIDE];   // < 393216  always valid (npairs=500000)
    const bool has3 = (pbase + 3 * PSTRIDE) < npairs;
    i32x2 pr3 = has3 ? pairs2[pbase + 3 * PSTRIDE] : (i32x2){0, 0};

    for (int j = tid; j < NRES; j += 256) {
        sx[j] = ca[3 * j + 0];
        sy[j] = ca[3 * j + 1];
        sz[j] = ca[3 * j + 2];
    }
    __syncthreads();

    // hoist all 4 chunks' column vectors + 8 row coords into registers
    float4 CX[4], CY[4], CZ[4];
#pragma unroll
    for (int c = 0; c < 4; ++c) {
        const int jc = j0 + (c << 10);
        CX[c] = *(const float4*)&sx[jc];
        CY[c] = *(const float4*)&sy[jc];
        CZ[c] = *(const float4*)&sz[jc];
    }
    float xi[TROWS], yi[TROWS], zi[TROWS];
#pragma unroll
    for (int r = 0; r < TROWS; ++r) {
        xi[r] = sx[rbase + r]; yi[r] = sy[rbase + r]; zi[r] = sz[rbase + r];
    }

    // ---------------- contact: 32 memory-ordered steps, 8-deep ring ----------------
    float contact = 0.f, contact2 = 0.f;
#pragma unroll
    for (int s = 0; s < 32; ++s) {
        const int r = s >> 2, c = s & 3;
        const float4 kv = ring[s & 7];
        if (s < 24)    // reload consumed slot with step s+8 (same memory-order walk)
            ring[s & 7] = ldnt(Kt + (size_t)((s + 8) >> 2) * NRES + (((s + 8) & 3) << 10) + j0);
        if (s & 1) contact2 = c4(kv, CX[c], CY[c], CZ[c], xi[r], yi[r], zi[r], contact2);
        else       contact  = c4(kv, CX[c], CY[c], CZ[c], xi[r], yi[r], zi[r], contact);
    }
    contact += contact2;

    // ---------------- clash: preloaded indices, gathers from LDS ----------------
    float clash = 0.f;
    {
        float dx, dy, dz, d, r;
        dx = sx[pr0.x] - sx[pr0.y]; dy = sy[pr0.x] - sy[pr0.y]; dz = sz[pr0.x] - sz[pr0.y];
        d = fsqrt(fmaxf(fmaf(dx, dx, fmaf(dy, dy, dz * dz)), 1e-12f));
        r = fmaxf(3.2f - d, 0.f); clash = fmaf(r, r, clash);

        dx = sx[pr1.x] - sx[pr1.y]; dy = sy[pr1.x] - sy[pr1.y]; dz = sz[pr1.x] - sz[pr1.y];
        d = fsqrt(fmaxf(fmaf(dx, dx, fmaf(dy, dy, dz * dz)), 1e-12f));
        r = fmaxf(3.2f - d, 0.f); clash = fmaf(r, r, clash);

        dx = sx[pr2.x] - sx[pr2.y]; dy = sy[pr2.x] - sy[pr2.y]; dz = sz[pr2.x] - sz[pr2.y];
        d = fsqrt(fmaxf(fmaf(dx, dx, fmaf(dy, dy, dz * dz)), 1e-12f));
        r = fmaxf(3.2f - d, 0.f); clash = fmaf(r, r, clash);

        if (has3) {
            dx = sx[pr3.x] - sx[pr3.y]; dy = sy[pr3.x] - sy[pr3.y]; dz = sz[pr3.x] - sz[pr3.y];
            d = fsqrt(fmaxf(fmaf(dx, dx, fmaf(dy, dy, dz * dz)), 1e-12f));
            r = fmaxf(3.2f - d, 0.f); clash = fmaf(r, r, clash);
        }
    }

    // ---------------- bond + hb: blocks 0..15, from LDS ----------------
    float bond = 0.f, hb = 0.f;
    if (b < HB_BLOCKS) {
        const int i = b * 256 + tid;
        const int n = NRES;

        if (i < n - 1) {
            float dx = sx[i+1]-sx[i], dy = sy[i+1]-sy[i], dz = sz[i+1]-sz[i];
            float d  = sqrtf(fmaf(dx, dx, fmaf(dy, dy, dz * dz)));
            float t  = d - 3.8f;
            bond = t * t;
        }

        if (i < n - 2) {
            float cax = sx[i], cay = sy[i], caz = sz[i];
            float vx = sx[i+1]-cax, vy = sy[i+1]-cay, vz = sz[i+1]-caz;
            float inv = 1.f / (sqrtf(vx*vx + vy*vy + vz*vz) + 1e-8f);
            float ux = vx*inv, uy = vy*inv, uz = vz*inv;

            float upx, upy, upz;
            if (i == 0) { upx = ux; upy = uy; upz = uz; }
            else {
                float wx = cax-sx[i-1], wy = cay-sy[i-1], wz = caz-sz[i-1];
                float inv2 = 1.f / (sqrtf(wx*wx + wy*wy + wz*wz) + 1e-8f);
                upx = wx*inv2; upy = wy*inv2; upz = wz*inv2;
            }

            float vcx = 0.38f*ux,  vcy = 0.38f*uy,  vcz = 0.38f*uz;
            float vnx = -0.38f*upx, vny = -0.38f*upy, vnz = -0.38f*upz;
            float px = vcy*vnz - vcz*vny;
            float py = vcz*vnx - vcx*vnz;
            float pz = vcx*vny - vcy*vnx;
            float pn = sqrtf(px*px + py*py + pz*pz);
            if (pn > 1e-6f) {
                float ipn = 1.f / fmaxf(pn, 1e-12f);
                px *= ipn; py *= ipn; pz *= ipn;
            }
            float ox = cax + vcx + 1.24f*px;
            float oy = cay + vcy + 1.24f*py;
            float oz = caz + vcz + 1.24f*pz;

#pragma unroll
            for (int off = 2; off <= 5; ++off) {
                int jj = i + off;
                if (jj < n) {
                    float cjx = sx[jj], cjy = sy[jj], cjz = sz[jj];
                    float qx = cjx-sx[jj-1], qy = cjy-sy[jj-1], qz = cjz-sz[jj-1];
                    float invq = 1.f / (sqrtf(qx*qx + qy*qy + qz*qz) + 1e-8f);
                    float njx = cjx - 0.38f*qx*invq;
                    float njy = cjy - 0.38f*qy*invq;
                    float njz = cjz - 0.38f*qz*invq;
                    float ddx = ox-njx, ddy = oy-njy, ddz = oz-njz;
                    float d = sqrtf(ddx*ddx + ddy*ddy + ddz*ddz);
                    if (d > 2.5f && d < 3.5f) {
                        float z = (d - 2.95f) * (1.0f / 0.3f);
                        hb -= 0.5f * expf(-z*z);
                    }
                }
            }
        }
    }

    // ---------------- block reduce -> partial[b] ----------------
    float vbo = wave_sum(bond);
    float vcl = wave_sum(clash);
    float vco = wave_sum(contact);
    float vhb = wave_sum(hb);
    const int wave = tid >> 6;
    if ((tid & 63) == 0) {
        red[wave][0] = vbo; red[wave][1] = vcl; red[wave][2] = vco; red[wave][3] = vhb;
    }
    __syncthreads();
    if (tid == 0) {
        float4 o;
        o.x = red[0][0] + red[1][0] + red[2][0] + red[3][0];
        o.y = red[0][1] + red[1][1] + red[2][1] + red[3][1];
        o.z = red[0][2] + red[1][2] + red[2][2] + red[3][2];
        o.w = red[0][3] + red[1][3] + red[2][3] + red[3][3];
        partial[b] = o;
    }
}

// ---- reduce GRID partials, apply weights ----
__global__ __launch_bounds__(256) void finalize_kernel(const float4* __restrict__ partial,
                                                       float* __restrict__ out,
                                                       int n, int npairs) {
    __shared__ float red[4][4];
    const int tid = threadIdx.x;
    float vb = 0.f, vc = 0.f, vk = 0.f, vh = 0.f;
#pragma unroll
    for (int s = 0; s < GRID; s += 256) {
        float4 a = partial[tid + s];
        vb += a.x; vc += a.y; vk += a.z; vh += a.w;
    }
    vb = wave_sum(vb); vc = wave_sum(vc); vk = wave_sum(vk); vh = wave_sum(vh);
    const int wave = tid >> 6;
    if ((tid & 63) == 0) {
        red[wave][0] = vb; red[wave][1] = vc; red[wave][2] = vk; red[wave][3] = vh;
    }
    __syncthreads();
    if (tid == 0) {
        float bond    = red[0][0] + red[1][0] + red[2][0] + red[3][0];
        float clash   = red[0][1] + red[1][1] + red[2][1] + red[3][1];
        float contact = red[0][2] + red[1][2] + red[2][2] + red[3][2];
        float hb      = red[0][3] + red[1][3] + red[2][3] + red[3][3];
        float inv_nn  = 1.f / ((float)n * (float)n);
        out[0] = 30.f * bond / (float)(n - 1)
               + 50.f * clash / (float)npairs
               + 5.f  * contact * inv_nn
               + 4.f  * hb * inv_nn;
    }
}

extern "C" void kernel_launch(void* const* d_in, const int* in_sizes, int n_in,
                              void* d_out, int out_size, void* d_ws, size_t ws_size,
                              hipStream_t stream) {
    const float* ca    = (const float*)d_in[0];
    const float* K     = (const float*)d_in[1];
    const int*   pairs = (const int*)d_in[2];   // int32 on device (x64 disabled)
    float* out = (float*)d_out;
    float4* partial = (float4*)d_ws;            // GRID float4 = 8 KB

    int n      = in_sizes[0] / 3;               // 4096
    int npairs = in_sizes[2] / 2;               // 500000

    energy_kernel<<<GRID, 256, 0, stream>>>(ca, K, pairs, partial, npairs);
    finalize_kernel<<<1, 256, 0, stream>>>(partial, out, n, npairs);
}

// Round 6
// 101.778 us; speedup vs baseline: 1.1204x; 1.0536x over previous
//
#include <hip/hip_runtime.h>
#include <math.h>

#define NRES   4096
#define TROWS  8
#define GRID   (NRES / TROWS)      // 512 blocks, exactly ONE 8-row tile each -> uniform per-CU work
#define HB_BLOCKS (NRES / 256)     // 16
#define PSTRIDE (GRID * 256)       // 131072

typedef int i32x2 __attribute__((ext_vector_type(2)));

__device__ __forceinline__ float wave_sum(float v) {
#pragma unroll
    for (int off = 32; off > 0; off >>= 1) v += __shfl_down(v, off, 64);
    return v;
}

// raw v_sqrt_f32 (≈1 ulp), skips libm's IEEE fixup sequence
__device__ __forceinline__ float fsqrt(float x) { return __builtin_amdgcn_sqrtf(x); }

// 4 contact terms: one K float4 vs 4 LDS columns
__device__ __forceinline__ float c4(float4 kv, float4 cx, float4 cy, float4 cz,
                                    float xi, float yi, float zi, float s) {
    float dx, dy, dz, D, t;
    dx = xi - cx.x; dy = yi - cy.x; dz = zi - cz.x;
    D  = fsqrt(fmaf(dx, dx, fmaf(dy, dy, dz * dz)));
    t  = fmaf(8.f, kv.x, D - 8.f);   // D - 8(1-k)
    s  = fmaf(t, t, s);

    dx = xi - cx.y; dy = yi - cy.y; dz = zi - cz.y;
    D  = fsqrt(fmaf(dx, dx, fmaf(dy, dy, dz * dz)));
    t  = fmaf(8.f, kv.y, D - 8.f);
    s  = fmaf(t, t, s);

    dx = xi - cx.z; dy = yi - cy.z; dz = zi - cz.z;
    D  = fsqrt(fmaf(dx, dx, fmaf(dy, dy, dz * dz)));
    t  = fmaf(8.f, kv.z, D - 8.f);
    s  = fmaf(t, t, s);

    dx = xi - cx.w; dy = yi - cy.w; dz = zi - cz.w;
    D  = fsqrt(fmaf(dx, dx, fmaf(dy, dy, dz * dz)));
    t  = fmaf(8.f, kv.w, D - 8.f);
    s  = fmaf(t, t, s);
    return s;
}

// PROVEN BEST (R1, 101.79us; R0-equivalent 101.59us). Session A/B history:
//  - zero-LDS (L1 gathers):        -12.2us  -> LDS ca table is load-bearing
//  - fused ticket+fence finalize:  -11.3us  -> keep 2-dispatch reduce
//  - memory-order walk + nt loads:  -5.4us  -> keep chunk-outer order, plain loads
//  - grid/balance variants:          0.0    -> schedule-insensitive
// One 8-row tile per block, 2 blocks/CU @ 96KB LDS; K streamed with plain
// loads (L3-resident after harness restore); chunk-0 K loads issued before
// the LDS fill so L3 latency hides under staging.
__global__ __launch_bounds__(256, 2) void energy_kernel(const float* __restrict__ ca,
                                                        const float* __restrict__ K,
                                                        const int* __restrict__ pairs,
                                                        float4* __restrict__ partial,
                                                        int npairs) {
    __shared__ float sx[NRES], sy[NRES], sz[NRES];   // 48 KB
    __shared__ float red[4][4];
    const int tid = threadIdx.x;
    const int b   = blockIdx.x;

    const int rbase = b * TROWS;
    const float* Kt = K + (size_t)rbase * NRES;
    const int j0 = tid << 2;

    // chunk-0 K loads in flight before LDS staging (no dependence on LDS)
    float4 va[TROWS], vb[TROWS];
#pragma unroll
    for (int r = 0; r < TROWS; ++r)
        va[r] = *(const float4*)(Kt + (size_t)r * NRES + j0);

    // preload clash pair indices (resolve after contact)
    const int pbase = b * 256 + tid;
    const i32x2* pairs2 = (const i32x2*)pairs;
    i32x2 pr0 = pairs2[pbase];                 // < 131072  always valid
    i32x2 pr1 = pairs2[pbase + PSTRIDE];       // < 262144  always valid
    i32x2 pr2 = pairs2[pbase + 2 * PSTRIDE];   // < 393216  always valid (npairs=500000)
    const bool has3 = (pbase + 3 * PSTRIDE) < npairs;
    i32x2 pr3 = has3 ? pairs2[pbase + 3 * PSTRIDE] : (i32x2){0, 0};

    for (int j = tid; j < NRES; j += 256) {
        sx[j] = ca[3 * j + 0];
        sy[j] = ca[3 * j + 1];
        sz[j] = ca[3 * j + 2];
    }
    __syncthreads();

    // ---------------- contact: single 8-row tile ----------------
    float xi[TROWS], yi[TROWS], zi[TROWS];
#pragma unroll
    for (int r = 0; r < TROWS; ++r) {
        xi[r] = sx[rbase + r]; yi[r] = sy[rbase + r]; zi[r] = sz[rbase + r];
    }

    float contact = 0.f, contact2 = 0.f;
#pragma unroll
    for (int c = 0; c < 4; ++c) {               // 4 column chunks of 1024
        const int jc = j0 + (c << 10);
        float4* cur = (c & 1) ? vb : va;
        float4* nxt = (c & 1) ? va : vb;
        if (c < 3) {
            const int jn = j0 + ((c + 1) << 10);
#pragma unroll
            for (int r = 0; r < TROWS; ++r)
                nxt[r] = *(const float4*)(Kt + (size_t)r * NRES + jn);
        }
        const float4 cx = *(const float4*)&sx[jc];
        const float4 cy = *(const float4*)&sy[jc];
        const float4 cz = *(const float4*)&sz[jc];
#pragma unroll
        for (int r = 0; r < TROWS; r += 2) {
            contact  = c4(cur[r],     cx, cy, cz, xi[r],     yi[r],     zi[r],     contact);
            contact2 = c4(cur[r + 1], cx, cy, cz, xi[r + 1], yi[r + 1], zi[r + 1], contact2);
        }
    }
    contact += contact2;

    // ---------------- clash: preloaded indices, gathers from LDS ----------------
    float clash = 0.f;
    {
        float dx, dy, dz, d, r;
        dx = sx[pr0.x] - sx[pr0.y]; dy = sy[pr0.x] - sy[pr0.y]; dz = sz[pr0.x] - sz[pr0.y];
        d = fsqrt(fmaxf(fmaf(dx, dx, fmaf(dy, dy, dz * dz)), 1e-12f));
        r = fmaxf(3.2f - d, 0.f); clash = fmaf(r, r, clash);

        dx = sx[pr1.x] - sx[pr1.y]; dy = sy[pr1.x] - sy[pr1.y]; dz = sz[pr1.x] - sz[pr1.y];
        d = fsqrt(fmaxf(fmaf(dx, dx, fmaf(dy, dy, dz * dz)), 1e-12f));
        r = fmaxf(3.2f - d, 0.f); clash = fmaf(r, r, clash);

        dx = sx[pr2.x] - sx[pr2.y]; dy = sy[pr2.x] - sy[pr2.y]; dz = sz[pr2.x] - sz[pr2.y];
        d = fsqrt(fmaxf(fmaf(dx, dx, fmaf(dy, dy, dz * dz)), 1e-12f));
        r = fmaxf(3.2f - d, 0.f); clash = fmaf(r, r, clash);

        if (has3) {
            dx = sx[pr3.x] - sx[pr3.y]; dy = sy[pr3.x] - sy[pr3.y]; dz = sz[pr3.x] - sz[pr3.y];
            d = fsqrt(fmaxf(fmaf(dx, dx, fmaf(dy, dy, dz * dz)), 1e-12f));
            r = fmaxf(3.2f - d, 0.f); clash = fmaf(r, r, clash);
        }
    }

    // ---------------- bond + hb: blocks 0..15, from LDS ----------------
    float bond = 0.f, hb = 0.f;
    if (b < HB_BLOCKS) {
        const int i = b * 256 + tid;
        const int n = NRES;

        if (i < n - 1) {
            float dx = sx[i+1]-sx[i], dy = sy[i+1]-sy[i], dz = sz[i+1]-sz[i];
            float d  = sqrtf(fmaf(dx, dx, fmaf(dy, dy, dz * dz)));
            float t  = d - 3.8f;
            bond = t * t;
        }

        if (i < n - 2) {
            float cax = sx[i], cay = sy[i], caz = sz[i];
            float vx = sx[i+1]-cax, vy = sy[i+1]-cay, vz = sz[i+1]-caz;
            float inv = 1.f / (sqrtf(vx*vx + vy*vy + vz*vz) + 1e-8f);
            float ux = vx*inv, uy = vy*inv, uz = vz*inv;

            float upx, upy, upz;
            if (i == 0) { upx = ux; upy = uy; upz = uz; }
            else {
                float wx = cax-sx[i-1], wy = cay-sy[i-1], wz = caz-sz[i-1];
                float inv2 = 1.f / (sqrtf(wx*wx + wy*wy + wz*wz) + 1e-8f);
                upx = wx*inv2; upy = wy*inv2; upz = wz*inv2;
            }

            float vcx = 0.38f*ux,  vcy = 0.38f*uy,  vcz = 0.38f*uz;
            float vnx = -0.38f*upx, vny = -0.38f*upy, vnz = -0.38f*upz;
            float px = vcy*vnz - vcz*vny;
            float py = vcz*vnx - vcx*vnz;
            float pz = vcx*vny - vcy*vnx;
            float pn = sqrtf(px*px + py*py + pz*pz);
            if (pn > 1e-6f) {
                float ipn = 1.f / fmaxf(pn, 1e-12f);
                px *= ipn; py *= ipn; pz *= ipn;
            }
            float ox = cax + vcx + 1.24f*px;
            float oy = cay + vcy + 1.24f*py;
            float oz = caz + vcz + 1.24f*pz;

#pragma unroll
            for (int off = 2; off <= 5; ++off) {
                int jj = i + off;
                if (jj < n) {
                    float cjx = sx[jj], cjy = sy[jj], cjz = sz[jj];
                    float qx = cjx-sx[jj-1], qy = cjy-sy[jj-1], qz = cjz-sz[jj-1];
                    float invq = 1.f / (sqrtf(qx*qx + qy*qy + qz*qz) + 1e-8f);
                    float njx = cjx - 0.38f*qx*invq;
                    float njy = cjy - 0.38f*qy*invq;
                    float njz = cjz - 0.38f*qz*invq;
                    float ddx = ox-njx, ddy = oy-njy, ddz = oz-njz;
                    float d = sqrtf(ddx*ddx + ddy*ddy + ddz*ddz);
                    if (d > 2.5f && d < 3.5f) {
                        float z = (d - 2.95f) * (1.0f / 0.3f);
                        hb -= 0.5f * expf(-z*z);
                    }
                }
            }
        }
    }

    // ---------------- block reduce -> partial[b] ----------------
    float vbo = wave_sum(bond);
    float vcl = wave_sum(clash);
    float vco = wave_sum(contact);
    float vhb = wave_sum(hb);
    const int wave = tid >> 6;
    if ((tid & 63) == 0) {
        red[wave][0] = vbo; red[wave][1] = vcl; red[wave][2] = vco; red[wave][3] = vhb;
    }
    __syncthreads();
    if (tid == 0) {
        float4 o;
        o.x = red[0][0] + red[1][0] + red[2][0] + red[3][0];
        o.y = red[0][1] + red[1][1] + red[2][1] + red[3][1];
        o.z = red[0][2] + red[1][2] + red[2][2] + red[3][2];
        o.w = red[0][3] + red[1][3] + red[2][3] + red[3][3];
        partial[b] = o;
    }
}

// ---- reduce GRID partials, apply weights ----
__global__ __launch_bounds__(256) void finalize_kernel(const float4* __restrict__ partial,
                                                       float* __restrict__ out,
                                                       int n, int npairs) {
    __shared__ float red[4][4];
    const int tid = threadIdx.x;
    float vb = 0.f, vc = 0.f, vk = 0.f, vh = 0.f;
#pragma unroll
    for (int s = 0; s < GRID; s += 256) {
        float4 a = partial[tid + s];
        vb += a.x; vc += a.y; vk += a.z; vh += a.w;
    }
    vb = wave_sum(vb); vc = wave_sum(vc); vk = wave_sum(vk); vh = wave_sum(vh);
    const int wave = tid >> 6;
    if ((tid & 63) == 0) {
        red[wave][0] = vb; red[wave][1] = vc; red[wave][2] = vk; red[wave][3] = vh;
    }
    __syncthreads();
    if (tid == 0) {
        float bond    = red[0][0] + red[1][0] + red[2][0] + red[3][0];
        float clash   = red[0][1] + red[1][1] + red[2][1] + red[3][1];
        float contact = red[0][2] + red[1][2] + red[2][2] + red[3][2];
        float hb      = red[0][3] + red[1][3] + red[2][3] + red[3][3];
        float inv_nn  = 1.f / ((float)n * (float)n);
        out[0] = 30.f * bond / (float)(n - 1)
               + 50.f * clash / (float)npairs
               + 5.f  * contact * inv_nn
               + 4.f  * hb * inv_nn;
    }
}

extern "C" void kernel_launch(void* const* d_in, const int* in_sizes, int n_in,
                              void* d_out, int out_size, void* d_ws, size_t ws_size,
                              hipStream_t stream) {
    const float* ca    = (const float*)d_in[0];
    const float* K     = (const float*)d_in[1];
    const int*   pairs = (const int*)d_in[2];   // int32 on device (x64 disabled)
    float* out = (float*)d_out;
    float4* partial = (float4*)d_ws;            // GRID float4 = 8 KB

    int n      = in_sizes[0] / 3;               // 4096
    int npairs = in_sizes[2] / 2;               // 500000

    energy_kernel<<<GRID, 256, 0, stream>>>(ca, K, pairs, partial, npairs);
    finalize_kernel<<<1, 256, 0, stream>>>(partial, out, n, npairs);
}